// Round 4
// baseline (1262.840 us; speedup 1.0000x reference)
//
#include <hip/hip_runtime.h>
#include <hip/hip_bf16.h>
#include <stdint.h>

// Problem constants
#define B_   4
#define S_   2048
#define H_   16
#define D_   64
#define DM_  1024
#define NTOK (B_ * S_)          // 8192 tokens

typedef __attribute__((ext_vector_type(8))) short short8;   // 8 bf16 (4 VGPRs)
typedef __attribute__((ext_vector_type(4))) float floatx4;  // MFMA C/D

__device__ inline unsigned short f2bf(float f) {
  // RNE float -> bf16 (finite inputs)
  unsigned int u = __float_as_uint(f);
  u += 0x7FFFu + ((u >> 16) & 1u);
  return (unsigned short)(u >> 16);
}

__device__ inline floatx4 mfma_bf16(short8 a, short8 b, floatx4 c) {
  return __builtin_amdgcn_mfma_f32_16x16x32_bf16(a, b, c, 0, 0, 0);
}

// pack two fp32 into bf16x2 (RTZ: high 16 bits of each) — one v_perm_b32
__device__ inline unsigned int pack_bf2(float lo, float hi) {
  return __builtin_amdgcn_perm(__float_as_uint(hi), __float_as_uint(lo), 0x07060302u);
}

// packed RNE fp32x2 -> bf16x2 (v_cvt_pk_bf16_f32 on gfx950 via HIP intrinsic)
__device__ inline unsigned int cvt_pk_bf16(float lo, float hi) {
  __hip_bfloat162 h = __float22bfloat162_rn(make_float2(lo, hi));
  return *(unsigned int*)&h;
}

// async global->LDS, 16B per lane; LDS dest = wave-uniform base + lane*16
template <typename T>
__device__ inline void gload_lds16(const T* g, T* l) {
  __builtin_amdgcn_global_load_lds(
      (const __attribute__((address_space(1))) unsigned int*)g,
      (__attribute__((address_space(3))) unsigned int*)l, 16, 0, 0);
}

// ---------------------------------------------------------------------------
// LDS-tiled weight cast+transpose: w[k][n] fp32 [1024x1024] -> wT[n][k] bf16.
// ---------------------------------------------------------------------------
__global__ __launch_bounds__(256) void wt_kernel(const float* __restrict__ w0,
                                                 const float* __restrict__ w1,
                                                 const float* __restrict__ w2,
                                                 const float* __restrict__ w3,
                                                 unsigned short* __restrict__ o0,
                                                 unsigned short* __restrict__ o1,
                                                 unsigned short* __restrict__ o2,
                                                 unsigned short* __restrict__ o3) {
  __shared__ unsigned short T[64 * 68];   // transposed tile [n][k], stride 68
  const float* w = blockIdx.z == 0 ? w0 : blockIdx.z == 1 ? w1 : blockIdx.z == 2 ? w2 : w3;
  unsigned short* o = blockIdx.z == 0 ? o0 : blockIdx.z == 1 ? o1 : blockIdx.z == 2 ? o2 : o3;
  const int tid = threadIdx.x;
  const int R0 = blockIdx.y * 64;   // k-block
  const int C0 = blockIdx.x * 64;   // n-block
  for (int it = 0; it < 16; it++) {
    int lr = it * 4 + (tid >> 6), lc = tid & 63;
    T[lc * 68 + lr] = f2bf(w[(size_t)(R0 + lr) * 1024 + C0 + lc]);
  }
  __syncthreads();
  for (int it = 0; it < 2; it++) {
    int orow = it * 32 + (tid >> 3), oc = (tid & 7) * 8;
    union { ushort4 h[2]; short8 v8; } u;
    u.h[0] = *(const ushort4*)(T + orow * 68 + oc);
    u.h[1] = *(const ushort4*)(T + orow * 68 + oc + 4);
    *(short8*)(o + (size_t)(C0 + orow) * 1024 + R0 + oc) = u.v8;
  }
}

// ---------------------------------------------------------------------------
// Fused QKV projection GEMM: z = blockIdx.x>>3 selects (Q,wq)->qP, (K,wk)->kP,
// (V,wv)->vTg(sigma). A is raw fp32 (cast kernels eliminated): staged via
// global_load_lds 16B (4 floats, XOR-swizzled chunks), converted to bf16 with
// packed RNE cvt during frag build. Single-barrier LDS double-buffer: prefetch
// of k-tile t+1 is in flight during compute of tile t.
// ---------------------------------------------------------------------------
__global__ __launch_bounds__(256) void gemm_qkv_kernel(
    const float* __restrict__ Qf, const float* __restrict__ Kf,
    const float* __restrict__ Vf,
    const unsigned short* __restrict__ wqT, const unsigned short* __restrict__ wkT,
    const unsigned short* __restrict__ wvT,
    unsigned short* __restrict__ qP, unsigned short* __restrict__ kP,
    unsigned short* __restrict__ vTg, float SC) {
  constexpr int K = 1024;
  __shared__ float          As[2][128 * 32];   // fp32 A tile, 16 KB x2
  __shared__ unsigned short Bs[2][128 * 32];   // bf16 B tile, 8 KB x2

  const int tid  = threadIdx.x;
  const int wave = tid >> 6, lane = tid & 63;
  const int quad = lane >> 4, l16 = lane & 15;
  const int wm = wave >> 1, wn = wave & 1;
  const int z  = blockIdx.x >> 3;             // which projection
  const int n0 = (blockIdx.x & 7) * 128;
  const int m0 = blockIdx.y * 128;

  const float* A = z == 0 ? Qf : z == 1 ? Kf : Vf;
  const unsigned short* BT = z == 0 ? wqT : z == 1 ? wkT : wvT;

  floatx4 acc[4][4] = {};

  auto stage = [&](int buf, int k0) {
    // A: 1024 chunks of 16B; slot i holds row r=i>>3, float-chunk (i&7)^(r&7)
    for (int p = 0; p < 4; p++) {
      int i = p * 256 + wave * 64 + lane;
      int r = i >> 3, gc = (i & 7) ^ (r & 7);
      gload_lds16(A + (size_t)(m0 + r) * K + k0 + gc * 4,
                  &As[buf][(p * 256 + wave * 64) * 4]);
    }
    // B: 512 chunks of 16B, linear (row r=i>>2, chunk i&3)
    for (int p = 0; p < 2; p++) {
      int i = p * 256 + wave * 64 + lane;
      int r = i >> 2, c = i & 3;
      gload_lds16(BT + (size_t)(n0 + r) * K + k0 + c * 8,
                  &Bs[buf][(p * 256 + wave * 64) * 8]);
    }
  };

  stage(0, 0);
  for (int kt = 0; kt < K / 32; kt++) {
    __syncthreads();                         // drains stage(kt); prior reads done
    if (kt + 1 < K / 32) stage((kt + 1) & 1, (kt + 1) * 32);
    const int cur = kt & 1;

    short8 af[4], bfr[4];
    for (int f = 0; f < 4; f++) {
      int row = wm * 64 + f * 16 + l16;
      int s0 = row * 8 + ((quad * 2)     ^ (row & 7));
      int s1 = row * 8 + ((quad * 2 + 1) ^ (row & 7));
      float4 a0 = *(const float4*)&As[cur][s0 * 4];
      float4 a1 = *(const float4*)&As[cur][s1 * 4];
      union { unsigned int u[4]; short8 v; } t;
      t.u[0] = cvt_pk_bf16(a0.x, a0.y);
      t.u[1] = cvt_pk_bf16(a0.z, a0.w);
      t.u[2] = cvt_pk_bf16(a1.x, a1.y);
      t.u[3] = cvt_pk_bf16(a1.z, a1.w);
      af[f]  = t.v;
      bfr[f] = *(const short8*)&Bs[cur][(wn * 64 + f * 16 + l16) * 32 + quad * 8];
    }
    for (int fm = 0; fm < 4; fm++)
      for (int fn = 0; fn < 4; fn++)
        acc[fm][fn] = mfma_bf16(af[fm], bfr[fn], acc[fm][fn]);
  }

  // epilogue: C row = quad*4+reg, col = lane&15
  for (int fm = 0; fm < 4; fm++)
    for (int fn = 0; fn < 4; fn++)
      for (int r = 0; r < 4; r++) {
        int gm = m0 + wm * 64 + fm * 16 + quad * 4 + r;
        int gn = n0 + wn * 64 + fn * 16 + l16;
        int b = gm >> 11, s = gm & 2047;
        int h = gn >> 6,  d = gn & 63;
        float val = acc[fm][fn][r];
        if (z == 0) {
          qP[((size_t)((b * H_ + h) * S_ + s) << 6) + d] = f2bf(val * SC);
        } else if (z == 1) {
          kP[((size_t)((b * H_ + h) * S_ + s) << 6) + d] = f2bf(val);
        } else {
          int p = ((s & 63) >> 4) + (s & 15) * 4;   // inv_sigma within 64-block
          vTg[(((size_t)(b * H_ + h) * 64 + d) << 11) + (s & ~63) + p] = f2bf(val);
        }
      }
}

// ---------------------------------------------------------------------------
// Output projection GEMM: C[8192,1024] fp32 = X[8192,1024]bf16 x woT^T.
// Same dbuf single-barrier structure, bf16 A.
// ---------------------------------------------------------------------------
__global__ __launch_bounds__(256) void gemm_out_kernel(const unsigned short* __restrict__ A,
                                                       const unsigned short* __restrict__ BT,
                                                       float* __restrict__ C) {
  constexpr int K = 1024;
  __shared__ unsigned short As[2][128 * 32];
  __shared__ unsigned short Bs[2][128 * 32];

  const int tid  = threadIdx.x;
  const int wave = tid >> 6, lane = tid & 63;
  const int quad = lane >> 4, l16 = lane & 15;
  const int wm = wave >> 1, wn = wave & 1;
  const int m0 = blockIdx.y * 128, n0 = blockIdx.x * 128;

  floatx4 acc[4][4] = {};

  auto stage = [&](int buf, int k0) {
    for (int p = 0; p < 2; p++) {
      int i = p * 256 + wave * 64 + lane;
      int r = i >> 2, c = i & 3;
      gload_lds16(A  + (size_t)(m0 + r) * K + k0 + c * 8,
                  &As[buf][(p * 256 + wave * 64) * 8]);
      gload_lds16(BT + (size_t)(n0 + r) * K + k0 + c * 8,
                  &Bs[buf][(p * 256 + wave * 64) * 8]);
    }
  };

  stage(0, 0);
  for (int kt = 0; kt < K / 32; kt++) {
    __syncthreads();
    if (kt + 1 < K / 32) stage((kt + 1) & 1, (kt + 1) * 32);
    const int cur = kt & 1;

    short8 af[4], bfr[4];
    for (int f = 0; f < 4; f++) {
      af[f]  = *(const short8*)&As[cur][(wm * 64 + f * 16 + l16) * 32 + quad * 8];
      bfr[f] = *(const short8*)&Bs[cur][(wn * 64 + f * 16 + l16) * 32 + quad * 8];
    }
    for (int fm = 0; fm < 4; fm++)
      for (int fn = 0; fn < 4; fn++)
        acc[fm][fn] = mfma_bf16(af[fm], bfr[fn], acc[fm][fn]);
  }

  for (int fm = 0; fm < 4; fm++)
    for (int fn = 0; fn < 4; fn++)
      for (int r = 0; r < 4; r++) {
        int gm = m0 + wm * 64 + fm * 16 + quad * 4 + r;
        int gn = n0 + wn * 64 + fn * 16 + l16;
        C[((size_t)gm << 10) + gn] = acc[fm][fn][r];
      }
}

// ---------------------------------------------------------------------------
// Flash attention v4: no-max exp2 softmax (raw v_exp_f32 via builtin), V
// pre-transposed+sigma-permuted in global, K/V^T staged via XOR-swizzled
// global_load_lds with single-barrier double-buffer (prefetch j+1 in flight
// during compute of j — the fix for 2-blocks/CU latency exposure). l via MFMA
// against ones-column (sums the SAME RTZ-truncated P -> normalization exact).
// ---------------------------------------------------------------------------
__global__ __launch_bounds__(256, 2) void attn_kernel(const unsigned short* __restrict__ q,
                                                      const unsigned short* __restrict__ k,
                                                      const unsigned short* __restrict__ vT,
                                                      unsigned short* __restrict__ X) {
  __shared__ unsigned short Ks[2][64 * 64];   // 8 KB x2, XOR-swizzled chunks
  __shared__ unsigned short Vt[2][64 * 64];   // 8 KB x2, XOR-swizzled chunks
  __shared__ unsigned short Ps[4][16 * 72];   // 9 KB, per-wave P tile, padded

  const int tid  = threadIdx.x;
  const int wave = tid >> 6, lane = tid & 63;
  const int quad = lane >> 4, l16 = lane & 15;
  const int bh = blockIdx.y;
  const int q0 = blockIdx.x * 256;

  const unsigned short* qh = q  + (size_t)bh * S_ * 64;
  const unsigned short* kh = k  + (size_t)bh * S_ * 64;
  const unsigned short* vh = vT + (size_t)bh * 64 * S_;   // [d][s']

  // Q fragments (A-layout), resident: 4 qt x 2 k-chunks
  short8 qf[4][2];
  for (int qt = 0; qt < 4; qt++) {
    int row = q0 + wave * 64 + qt * 16 + l16;
    for (int kk = 0; kk < 2; kk++)
      qf[qt][kk] = *(const short8*)(qh + (size_t)row * 64 + kk * 32 + quad * 8);
  }

  // ones-column B-frag: B[k][n] = (n==0) ? 1 : 0
  short8 onesb = {};
  if (l16 == 0)
    for (int e = 0; e < 8; e++) onesb[e] = (short)0x3F80;

  floatx4 O[4][4] = {};
  floatx4 lacc[4] = {};

  auto stage = [&](int buf, int j0) {
    for (int p = 0; p < 2; p++) {
      int i = p * 256 + tid;
      int r = i >> 3;
      int gc = (i & 7) ^ (r & 7);
      gload_lds16(kh + (size_t)(j0 + r) * 64 + gc * 8,
                  &Ks[buf][(size_t)(p * 256 + wave * 64) * 8]);
      gload_lds16(vh + (size_t)r * S_ + j0 + gc * 8,
                  &Vt[buf][(size_t)(p * 256 + wave * 64) * 8]);
    }
  };

  stage(0, 0);
  for (int jt = 0; jt < S_ / 64; jt++) {
    __syncthreads();                          // stage(jt) done; prior reads done
    if (jt + 1 < S_ / 64) stage((jt + 1) & 1, (jt + 1) * 64);
    const int cur = jt & 1;

    // K frags (B-layout: n=j=jf*16+l16, k=d): undo swizzle
    short8 kf[4][2];
    for (int jf = 0; jf < 4; jf++)
      for (int kk = 0; kk < 2; kk++) {
        int sl = (kk * 4 + quad) ^ (l16 & 7);
        kf[jf][kk] = *(const short8*)&Ks[cur][(jf * 16 + l16) * 64 + sl * 8];
      }
    // V frags (B-layout: n=d=df*16+l16, k=sigma-slot j)
    short8 vf[4][2];
    for (int df = 0; df < 4; df++)
      for (int jk = 0; jk < 2; jk++) {
        int sl = (jk * 4 + quad) ^ (l16 & 7);
        vf[df][jk] = *(const short8*)&Vt[cur][(df * 16 + l16) * 64 + sl * 8];
      }

    unsigned short* pw = Ps[wave];
    for (int qt = 0; qt < 4; qt++) {
      floatx4 s[4] = {};
      for (int jf = 0; jf < 4; jf++) {
        s[jf] = mfma_bf16(qf[qt][0], kf[jf][0], s[jf]);
        s[jf] = mfma_bf16(qf[qt][1], kf[jf][1], s[jf]);
      }
      // p = exp2(score) (q pre-scaled by log2e/sqrt(dk)); RTZ-pack to bf16.
      for (int r = 0; r < 4; r++) {
        float e0 = __builtin_amdgcn_exp2f(s[0][r]);
        float e1 = __builtin_amdgcn_exp2f(s[1][r]);
        float e2 = __builtin_amdgcn_exp2f(s[2][r]);
        float e3 = __builtin_amdgcn_exp2f(s[3][r]);
        uint2 pk;
        pk.x = pack_bf2(e0, e1);
        pk.y = pack_bf2(e2, e3);
        *(uint2*)(pw + (quad * 4 + r) * 72 + l16 * 4) = pk;
      }
      short8 pa0 = *(const short8*)(pw + l16 * 72 + quad * 8);
      short8 pa1 = *(const short8*)(pw + l16 * 72 + 32 + quad * 8);
      lacc[qt] = mfma_bf16(pa0, onesb, lacc[qt]);
      lacc[qt] = mfma_bf16(pa1, onesb, lacc[qt]);
      for (int df = 0; df < 4; df++) {
        O[qt][df] = mfma_bf16(pa0, vf[df][0], O[qt][df]);
        O[qt][df] = mfma_bf16(pa1, vf[df][1], O[qt][df]);
      }
    }
  }

  // epilogue: l lives in lane quad*16 (col 0), reg r; broadcast, divide, store
  const int b = bh >> 4, h = bh & 15;
  for (int qt = 0; qt < 4; qt++)
    for (int r = 0; r < 4; r++) {
      float lsum = __shfl(lacc[qt][r], (lane & 48));
      float inv = 1.0f / lsum;
      int row = q0 + wave * 64 + qt * 16 + quad * 4 + r;
      unsigned short* dst = X + ((size_t)(b * S_ + row) << 10) + h * 64;
      for (int df = 0; df < 4; df++)
        dst[df * 16 + l16] = f2bf(O[qt][df][r] * inv);
    }
}

// ---------------------------------------------------------------------------
extern "C" void kernel_launch(void* const* d_in, const int* in_sizes, int n_in,
                              void* d_out, int out_size, void* d_ws, size_t ws_size,
                              hipStream_t stream) {
  const float* Q  = (const float*)d_in[0];
  const float* K  = (const float*)d_in[1];
  const float* V  = (const float*)d_in[2];
  const float* wq = (const float*)d_in[3];
  const float* wk = (const float*)d_in[4];
  const float* wv = (const float*)d_in[5];
  const float* wo = (const float*)d_in[6];

  char* ws = (char*)d_ws;
  unsigned short* buf0 = (unsigned short*)ws;                        // X, 16 MB
  unsigned short* wqT  = (unsigned short*)(ws + (size_t)(16 << 20));
  unsigned short* wkT  = (unsigned short*)(ws + (size_t)(18 << 20));
  unsigned short* wvT  = (unsigned short*)(ws + (size_t)(20 << 20));
  unsigned short* woT  = (unsigned short*)(ws + (size_t)(22 << 20));
  unsigned short* qP   = (unsigned short*)(ws + (size_t)(24 << 20));  // [B,H,S,64]
  unsigned short* kP   = (unsigned short*)(ws + (size_t)(40 << 20));  // [B,H,S,64]
  unsigned short* vTg  = (unsigned short*)(ws + (size_t)(56 << 20));  // [B,H,64,S] sigma

  const float SC = 0.18033688011112043f;   // log2(e) / sqrt(64), folded into q

  wt_kernel<<<dim3(16, 16, 4), dim3(256), 0, stream>>>(wq, wk, wv, wo, wqT, wkT, wvT, woT);

  gemm_qkv_kernel<<<dim3(24, 64), dim3(256), 0, stream>>>(Q, K, V, wqT, wkT, wvT,
                                                          qP, kP, vTg, SC);

  attn_kernel<<<dim3(8, 64), dim3(256), 0, stream>>>(qP, kP, vTg, buf0);

  gemm_out_kernel<<<dim3(8, 64), dim3(256), 0, stream>>>(buf0, woT, (float*)d_out);
}